// Round 11
// baseline (384.624 us; speedup 1.0000x reference)
//
#include <hip/hip_runtime.h>
#include <hip/hip_bf16.h>

#define BATCH 2
#define SEQ   2048
#define CH    1024
#define NH    16
#define HD    64
#define BHN   (BATCH*NH)   /* 32 */
#define SD    (SEQ*HD)     /* 131072 */

typedef short v8s __attribute__((ext_vector_type(8)));
typedef short v4s __attribute__((ext_vector_type(4)));
typedef float v4f __attribute__((ext_vector_type(4)));

__device__ __forceinline__ short f2bf(float f) {
    unsigned u = __float_as_uint(f);
    u += 0x7fff + ((u >> 16) & 1);   // RNE; finite inputs
    return (short)(u >> 16);
}

// packed RNE: returns (bf16(a) | bf16(b)<<16) via v_cvt_pk_bf16_f32
__device__ __forceinline__ unsigned pk2bf(float a, float b) {
    __hip_bfloat162 h = __float22bfloat162_rn(make_float2(a, b));
    unsigned u;
    __builtin_memcpy(&u, &h, 4);
    return u;
}

__device__ __forceinline__ void gl_lds16(const short* g, short* l) {
    __builtin_amdgcn_global_load_lds(
        (const __attribute__((address_space(1))) void*)g,
        (__attribute__((address_space(3))) void*)l, 16, 0, 0);
}

// ---------------------------------------------------------------------------
// Fused fp32 -> bf16 cast for src / Wq / Wk / Wv / rel_k_table.
// ---------------------------------------------------------------------------
__global__ __launch_bounds__(256) void cast_all_kernel(
    const float* __restrict__ src, const float* __restrict__ wq,
    const float* __restrict__ wk, const float* __restrict__ wv,
    const float* __restrict__ rel,
    short* __restrict__ xb, short* __restrict__ wqb,
    short* __restrict__ wkb, short* __restrict__ wvb,
    short* __restrict__ relb)
{
    const int z = blockIdx.z;
    const float* s; short* d; int n4;
    switch (z) {
        case 0: s = src; d = xb;   n4 = 1048576; break;  // 4Mi elems
        case 1: s = wq;  d = wqb;  n4 = 262144;  break;
        case 2: s = wk;  d = wkb;  n4 = 262144;  break;
        case 3: s = wv;  d = wvb;  n4 = 262144;  break;
        default: s = rel; d = relb; n4 = 65520;  break;  // 4095*64/4
    }
    for (int i = blockIdx.x * 256 + threadIdx.x; i < n4; i += gridDim.x * 256) {
        float4 v = ((const float4*)s)[i];
        v4s o; o.x = f2bf(v.x); o.y = f2bf(v.y); o.z = f2bf(v.z); o.w = f2bf(v.w);
        ((v4s*)d)[i] = o;
    }
}

// ---------------------------------------------------------------------------
// bf16 MFMA projection GEMM: out[m][n] = sum_k X[m][k]*W[n][k] + bias[n]
// M=4096, N=K=1024. 128x128 tile, BK=32, global_load_lds width 16.
// z==0 (Q): result pre-scaled by 0.125 (exact in bf16, exponent shift).
// ---------------------------------------------------------------------------
__global__ __launch_bounds__(256, 3) void proj_mfma_kernel(
    const short* __restrict__ Xb,
    const short* __restrict__ Wqb, const short* __restrict__ Wkb,
    const short* __restrict__ Wvb,
    const float* __restrict__ bq, const float* __restrict__ bk,
    const float* __restrict__ bv,
    short* __restrict__ qo, short* __restrict__ ko, short* __restrict__ vo)
{
    const int z = blockIdx.z;
    const short* W    = (z == 0) ? Wqb : (z == 1) ? Wkb : Wvb;
    const float* bias = (z == 0) ? bq  : (z == 1) ? bk  : bv;
    short*       out  = (z == 0) ? qo  : (z == 1) ? ko  : vo;
    const float  osc  = (z == 0) ? 0.125f : 1.0f;

    const int m0 = blockIdx.y * 128;
    const int n0 = blockIdx.x * 128;
    const int tid  = threadIdx.x;
    const int w    = tid >> 6;
    const int lane = tid & 63;
    const int l15  = lane & 15;
    const int quad = lane >> 4;
    const int wm = w & 1, wn = w >> 1;

    __shared__ short Al[128 * 32];   // [row][k], stride 32 (no pad: glds)
    __shared__ short Bl[128 * 32];

    v4f acc[4][4];
#pragma unroll
    for (int i = 0; i < 4; i++)
#pragma unroll
        for (int j = 0; j < 4; j++) acc[i][j] = (v4f)(0.f);

    const int lr = lane >> 2;          // 0..15 row-within-slab
    const int lc = (lane & 3) * 8;     // k-offset

    for (int k0 = 0; k0 < 1024; k0 += 32) {
        __syncthreads();
#pragma unroll
        for (int l = 0; l < 2; l++) {
            const int slab = w * 32 + l * 16;
            gl_lds16(Xb + (size_t)(m0 + slab + lr) * 1024 + k0 + lc,
                     &Al[slab * 32]);
            gl_lds16(W + (size_t)(n0 + slab + lr) * 1024 + k0 + lc,
                     &Bl[slab * 32]);
        }
        __syncthreads();
        v8s af[4], bf[4];
#pragma unroll
        for (int mt = 0; mt < 4; mt++)
            af[mt] = *(const v8s*)&Al[(wm * 64 + mt * 16 + l15) * 32 + quad * 8];
#pragma unroll
        for (int nt = 0; nt < 4; nt++)
            bf[nt] = *(const v8s*)&Bl[(wn * 64 + nt * 16 + l15) * 32 + quad * 8];
#pragma unroll
        for (int mt = 0; mt < 4; mt++)
#pragma unroll
            for (int nt = 0; nt < 4; nt++)
                acc[mt][nt] = __builtin_amdgcn_mfma_f32_16x16x32_bf16(
                    af[mt], bf[nt], acc[mt][nt], 0, 0, 0);
    }

    float bv4[4];
#pragma unroll
    for (int nt = 0; nt < 4; nt++)
        bv4[nt] = bias[n0 + wn * 64 + nt * 16 + l15];
#pragma unroll
    for (int mt = 0; mt < 4; mt++)
#pragma unroll
        for (int rg = 0; rg < 4; rg++) {
            const int row = m0 + wm * 64 + mt * 16 + quad * 4 + rg;
#pragma unroll
            for (int nt = 0; nt < 4; nt++)
                out[(size_t)row * 1024 + n0 + wn * 64 + nt * 16 + l15] =
                    f2bf((acc[mt][nt][rg] + bv4[nt]) * osc);
        }
}

// ---------------------------------------------------------------------------
// V transpose per (b,h): vt[bh][d][t] = v[bh][t][d].  64x64 LDS tiles.
// ---------------------------------------------------------------------------
__global__ __launch_bounds__(256) void vtrans_kernel(
    const short* __restrict__ v, short* __restrict__ vt)
{
    const int bh = blockIdx.y;
    const int t0 = blockIdx.x * 64;
    const int r = threadIdx.x >> 3;          // 0..31
    const int c = (threadIdx.x & 7) * 8;     // 0..56

    __shared__ short T[64][72];
    *(v8s*)&T[r][c] =
        *(const v8s*)(v + (size_t)bh * SD + (size_t)(t0 + r) * HD + c);
    *(v8s*)&T[r + 32][c] =
        *(const v8s*)(v + (size_t)bh * SD + (size_t)(t0 + r + 32) * HD + c);
    __syncthreads();
    v8s o0, o1;
#pragma unroll
    for (int e = 0; e < 8; e++) {
        o0[e] = T[c + e][r];
        o1[e] = T[c + e][r + 32];
    }
    *(v8s*)(vt + (size_t)bh * SD + (size_t)r * SEQ + t0 + c) = o0;
    *(v8s*)(vt + (size_t)bh * SD + (size_t)(r + 32) * SEQ + t0 + c) = o1;
}

// ---------------------------------------------------------------------------
// MFMA flash attention with relative-position scores (bf16 inputs; q tensor
// pre-scaled by 1/8 in the projection).
//   score[i][t] = qs[i]·k[t] + qrs[i]·rel[t-i+2047]
//
// R11 (on the R10 8-wave/512-thread structure): two exposed-latency fixes.
// (a) Next-tile K/V^T global loads now issue AFTER __syncthreads — the HIP
//     compiler drains vmcnt(0) at every barrier, so issuing them before the
//     barrier (R7-R10) stalled every wave on the prefetch every iteration.
//     Now they fly across the whole compute phase; the wait lands at the
//     consuming ds_write at loop bottom.
// (b) rel B-fragments are prefetched ONE FULL ITERATION ahead into registers
//     (loop unrolled x2, alternating rfA/rfB; prefetch rows clamped to
//     [0,4094] — in-window rows are <=4078 so used values are unaffected).
// Everything else identical to R10: dbuf K/V^T staging shared by 8 waves,
// 1 barrier/tile, skew gather via packed-bf16 bpermute, no online softmax
// (scores bounded, fp32-safe), lane-local row-sums reduced in epilogue.
// ---------------------------------------------------------------------------
__global__ __launch_bounds__(512, 4) void attn_mfma_kernel(
    const short* __restrict__ qb, const short* __restrict__ kb,
    const short* __restrict__ vtb, const short* __restrict__ relb,
    float* __restrict__ out)
{
    const int tid  = threadIdx.x;
    const int w    = tid >> 6;               // 0..7
    const int lane = tid & 63;
    const int l15  = lane & 15;
    const int quad = lane >> 4;
    const int bh = blockIdx.y, b = bh >> 4, h = bh & 15;
    const int s0 = blockIdx.x * 128;
    const int i0 = w * 16;

    __shared__ short Kl[2][64][72];      // key tile, double-buffered
    __shared__ short Vl[2][64][72];      // V^T tile, double-buffered
    __shared__ short Pb[8][16][76];      // per-wave P (bf16), PV A-operand

    // ---- loop-invariant q fragments (both views) ----
    v8s qc_f[2], qr_f[2];
#pragma unroll
    for (int kh = 0; kh < 2; kh++) {
        const int row = s0 + i0 + l15;
        qc_f[kh] = *(const v8s*)(qb + (size_t)bh * SD +
                                 (size_t)row * HD + kh * 32 + quad * 8);
        qr_f[kh] = *(const v8s*)(qb + (size_t)row * (BHN * HD) +
                                 bh * HD + kh * 32 + quad * 8);
    }
    // rel row base (row = brow[jt] + t, clamped to [0,4094] at load)
    int brow[5];
#pragma unroll
    for (int jt = 0; jt < 5; jt++)
        brow[jt] = 2032 - s0 - i0 + jt * 16 + l15;

    // ---- loop-invariant gather selectors ----
    int  slv[4];
    bool elo[4];
#pragma unroll
    for (int rg = 0; rg < 4; rg++) {
        const int ii = quad * 4 + rg;
        const int e  = l15 + 15 - ii;          // [0,30]
        slv[rg] = quad * 16 + (e & 15);
        elo[rg] = (e < 16);
    }

    v4f o_acc[4];
#pragma unroll
    for (int nt = 0; nt < 4; nt++) o_acc[nt] = (v4f)(0.f);
    float lpart[4] = {0.f, 0.f, 0.f, 0.f};

    // staging map: 512 threads cover one 64x64 tile: row = tid>>3, col=(tid&7)*8
    const int sr = tid >> 3, sc = (tid & 7) * 8;
    const short* kstb = kb + (size_t)bh * SD + (size_t)sr * HD + sc;
    const short* vstb = vtb + (size_t)bh * SD + (size_t)sr * SEQ + sc;

    // ---- prologue: stage tile 0 into buffer 0; rel prefetch for tile 0 ----
    {
        v8s k0 = *(const v8s*)kstb;
        v8s v0 = *(const v8s*)vstb;
        *(v8s*)&Kl[0][sr][sc] = k0;
        *(v8s*)&Vl[0][sr][sc] = v0;
    }
    v8s rfA[2][5], rfB[2][5];
#pragma unroll
    for (int kh = 0; kh < 2; kh++)
#pragma unroll
        for (int jt = 0; jt < 5; jt++) {
            int row = min(brow[jt], 4094);
            rfA[kh][jt] = *(const v8s*)(relb + (size_t)row * HD +
                                        kh * 32 + quad * 8);
        }

#define ATTN_TILE(T0, CUR, RF_USE, RF_PRE)                                     \
    {                                                                          \
        __syncthreads();  /* buf[CUR] staged; prior buf reads done */          \
        /* (a) next-tile loads AFTER the barrier: in flight during compute */  \
        const int tn = ((T0) + 64 < SEQ) ? (T0) + 64 : 0;                      \
        v8s nk0 = *(const v8s*)(kstb + (size_t)tn * HD);                       \
        v8s nv0 = *(const v8s*)(vstb + tn);                                    \
        /* (b) rel prefetch for NEXT tile into RF_PRE */                       \
        _Pragma("unroll")                                                      \
        for (int kh = 0; kh < 2; kh++)                                         \
            _Pragma("unroll")                                                  \
            for (int jt = 0; jt < 5; jt++) {                                   \
                int row = min(brow[jt] + (T0) + 64, 4094);                     \
                RF_PRE[kh][jt] = *(const v8s*)(relb + (size_t)row * HD +       \
                                               kh * 32 + quad * 8);            \
            }                                                                  \
        v4f cacc[4], racc[5];                                                  \
        _Pragma("unroll")                                                      \
        for (int nt = 0; nt < 4; nt++) cacc[nt] = (v4f)(0.f);                  \
        _Pragma("unroll")                                                      \
        for (int jt = 0; jt < 5; jt++) racc[jt] = (v4f)(0.f);                  \
        _Pragma("unroll")                                                      \
        for (int kh = 0; kh < 2; kh++) {                                       \
            v8s kf[4];                                                         \
            _Pragma("unroll")                                                  \
            for (int nt = 0; nt < 4; nt++)                                     \
                kf[nt] = *(const v8s*)&Kl[CUR][nt * 16 + l15]                  \
                                        [kh * 32 + quad * 8];                  \
            _Pragma("unroll")                                                  \
            for (int nt = 0; nt < 4; nt++)                                     \
                cacc[nt] = __builtin_amdgcn_mfma_f32_16x16x32_bf16(            \
                    qc_f[kh], kf[nt], cacc[nt], 0, 0, 0);                      \
            _Pragma("unroll")                                                  \
            for (int jt = 0; jt < 5; jt++)                                     \
                racc[jt] = __builtin_amdgcn_mfma_f32_16x16x32_bf16(            \
                    qr_f[kh], RF_USE[kh][jt], racc[jt], 0, 0, 0);              \
        }                                                                      \
        unsigned g01[4], g23[4], g4v[4];                                       \
        _Pragma("unroll")                                                      \
        for (int rg = 0; rg < 4; rg++) {                                       \
            unsigned p01 = pk2bf(racc[0][rg], racc[1][rg]);                    \
            unsigned p23 = pk2bf(racc[2][rg], racc[3][rg]);                    \
            unsigned p4  = (unsigned)(unsigned short)f2bf(racc[4][rg]);        \
            g01[rg] = (unsigned)__shfl((int)p01, slv[rg]);                     \
            g23[rg] = (unsigned)__shfl((int)p23, slv[rg]);                     \
            g4v[rg] = (unsigned)__shfl((int)p4,  slv[rg]);                     \
        }                                                                      \
        _Pragma("unroll")                                                      \
        for (int rg = 0; rg < 4; rg++) {                                       \
            const int ii = quad * 4 + rg;                                      \
            const unsigned a01 = g01[rg], a23 = g23[rg], a4 = g4v[rg];         \
            unsigned pb0 = elo[rg] ? (a01 << 16) : (a01 & 0xffff0000u);        \
            unsigned pb1 = elo[rg] ? (a01 & 0xffff0000u) : (a23 << 16);        \
            unsigned pb2 = elo[rg] ? (a23 << 16) : (a23 & 0xffff0000u);        \
            unsigned pb3 = elo[rg] ? (a23 & 0xffff0000u) : (a4  << 16);        \
            float p0 = __expf(cacc[0][rg] + __uint_as_float(pb0));             \
            float p1 = __expf(cacc[1][rg] + __uint_as_float(pb1));             \
            float p2 = __expf(cacc[2][rg] + __uint_as_float(pb2));             \
            float p3 = __expf(cacc[3][rg] + __uint_as_float(pb3));             \
            lpart[rg] += (p0 + p1) + (p2 + p3);                                \
            Pb[w][ii][l15]      = f2bf(p0);                                    \
            Pb[w][ii][16 + l15] = f2bf(p1);                                    \
            Pb[w][ii][32 + l15] = f2bf(p2);                                    \
            Pb[w][ii][48 + l15] = f2bf(p3);                                    \
        }                                                                      \
        _Pragma("unroll")                                                      \
        for (int kh = 0; kh < 2; kh++) {                                       \
            v8s pa = *(const v8s*)&Pb[w][l15][kh * 32 + quad * 8];             \
            _Pragma("unroll")                                                  \
            for (int nt = 0; nt < 4; nt++) {                                   \
                v8s vf = *(const v8s*)&Vl[CUR][nt * 16 + l15]                  \
                                        [kh * 32 + quad * 8];                  \
                o_acc[nt] = __builtin_amdgcn_mfma_f32_16x16x32_bf16(           \
                    pa, vf, o_acc[nt], 0, 0, 0);                               \
            }                                                                  \
        }                                                                      \
        *(v8s*)&Kl[(CUR) ^ 1][sr][sc] = nk0;                                   \
        *(v8s*)&Vl[(CUR) ^ 1][sr][sc] = nv0;                                   \
    }

    for (int t0 = 0; t0 < SEQ; t0 += 128) {
        ATTN_TILE(t0,      0, rfA, rfB)
        ATTN_TILE(t0 + 64, 1, rfB, rfA)
    }
#undef ATTN_TILE

    // ---- epilogue: one row-sum reduction, then normalized store ----
#pragma unroll
    for (int rg = 0; rg < 4; rg++) {
        float rs = lpart[rg];
#pragma unroll
        for (int off = 1; off < 16; off <<= 1)
            rs += __shfl_xor(rs, off);
        const float inv = 1.f / rs;
        const int row = s0 + i0 + quad * 4 + rg;
        const size_t base = ((size_t)b * SEQ + row) * CH + h * HD;
#pragma unroll
        for (int nt = 0; nt < 4; nt++)
            out[base + nt * 16 + l15] = o_acc[nt][rg] * inv;
    }
}

// ---------------------------------------------------------------------------
extern "C" void kernel_launch(void* const* d_in, const int* in_sizes, int n_in,
                              void* d_out, int out_size, void* d_ws, size_t ws_size,
                              hipStream_t stream)
{
    const float* src  = (const float*)d_in[0];
    const float* Wq   = (const float*)d_in[1];
    const float* bq   = (const float*)d_in[2];
    const float* Wk   = (const float*)d_in[3];
    const float* bk   = (const float*)d_in[4];
    const float* Wv   = (const float*)d_in[5];
    const float* bv   = (const float*)d_in[6];
    const float* relk = (const float*)d_in[7];
    float* out = (float*)d_out;

    const size_t nQKV = (size_t)BATCH * SEQ * CH;      // 4 Mi elements
    const size_t nW   = (size_t)CH * CH;               // 1 Mi
    short* qb   = (short*)d_ws;
    short* kb   = qb + nQKV;
    short* vb   = kb + nQKV;
    short* vtb  = vb + nQKV;
    short* xb   = vtb + nQKV;
    short* wqb  = xb + nQKV;
    short* wkb  = wqb + nW;
    short* wvb  = wkb + nW;
    short* relb = wvb + nW;                            // 4095*64 bf16

    cast_all_kernel<<<dim3(512, 1, 5), 256, 0, stream>>>(
        src, Wq, Wk, Wv, relk, xb, wqb, wkb, wvb, relb);

    dim3 gProj(1024 / 128, 4096 / 128, 3);             // (8, 32, 3)
    proj_mfma_kernel<<<gProj, 256, 0, stream>>>(
        xb, wqb, wkb, wvb, bq, bk, bv, qb, kb, vb);

    dim3 gVt(SEQ / 64, BHN);                           // (32, 32)
    vtrans_kernel<<<gVt, 256, 0, stream>>>(vb, vtb);

    dim3 gAttn(SEQ / 128, BHN);                        // (16, 32)
    attn_mfma_kernel<<<gAttn, 512, 0, stream>>>(qb, kb, vtb, relb, out);
}